// Round 6
// baseline (95.456 us; speedup 1.0000x reference)
//
#include <hip/hip_runtime.h>
#include <hip/hip_bf16.h>
#include <math.h>

#define N_NODES 156
#define NFEAT 256
#define NHID 128
#define BATCH 16384
#define TT 24
#define HLSTM 32
#define G4 128            // 4*HLSTM
#define ALPHA 0.2f
#define NW 2              // waves per block
#define ROWS_B (NW*16)    // batch rows per block
#define XSTRIDE (TT*N_NODES)   // 3744 floats per batch row
#define SLOTF 2496        // floats per (wave, slot): exactly 16 rows x 156

typedef __attribute__((ext_vector_type(8))) short bf16x8;
typedef __attribute__((ext_vector_type(4))) float f32x4;

static __device__ __forceinline__ unsigned short f2bf(float f) {
    unsigned u = __float_as_uint(f);
    u += 0x7fffu + ((u >> 16) & 1u);          // RNE
    return (unsigned short)(u >> 16);
}
static __device__ __forceinline__ bf16x8 cv8(float4 a, float4 b) {
    union { __hip_bfloat16 h[8]; bf16x8 v; } u;
    u.h[0] = __float2bfloat16(a.x); u.h[1] = __float2bfloat16(a.y);
    u.h[2] = __float2bfloat16(a.z); u.h[3] = __float2bfloat16(a.w);
    u.h[4] = __float2bfloat16(b.x); u.h[5] = __float2bfloat16(b.y);
    u.h[6] = __float2bfloat16(b.z); u.h[7] = __float2bfloat16(b.w);
    return u.v;
}
static __device__ __forceinline__ float sigm(float x) { return 1.f / (1.f + __expf(-x)); }
static __device__ __forceinline__ float tanh_(float x) { return 1.f - 2.f / (__expf(2.f * x) + 1.f); }

// ---------------- K1: GAT s1/s2 ----
__global__ void k_gat_s(const float* __restrict__ emb,
                        const float* __restrict__ Wr, const float* __restrict__ ar,
                        const float* __restrict__ Wp, const float* __restrict__ ap,
                        float* __restrict__ s_buf /* [2][2][156] */) {
    int i = blockIdx.x;
    int gat = blockIdx.y;
    const float* W = gat ? Wp : Wr;
    const float* a = gat ? ap : ar;
    int j = threadIdx.x; // 0..127
    __shared__ float erow[NFEAT];
    __shared__ float red[128];
    for (int k = j; k < NFEAT; k += 128) erow[k] = emb[i*NFEAT + k];
    __syncthreads();
    float h = 0.f;
    for (int k = 0; k < NFEAT; ++k) h = fmaf(erow[k], W[k*NHID + j], h);
    float v1 = h * a[j];
    float v2 = h * a[NHID + j];
    red[j] = v1; __syncthreads();
    for (int s = 64; s > 0; s >>= 1) { if (j < s) red[j] += red[j+s]; __syncthreads(); }
    if (j == 0) s_buf[(gat*2+0)*N_NODES + i] = red[0];
    __syncthreads();
    red[j] = v2; __syncthreads();
    for (int s = 64; s > 0; s >>= 1) { if (j < s) red[j] += red[j+s]; __syncthreads(); }
    if (j == 0) s_buf[(gat*2+1)*N_NODES + i] = red[0];
}

// ---------------- K2: masked leaky-relu softmax rows -> attn ----------------
__global__ void k_attn(const float* __restrict__ s_buf, const int* __restrict__ adj,
                       float* __restrict__ attn /* [2][156][156] */) {
    int i = blockIdx.x, gat = blockIdx.y;
    int j = threadIdx.x;
    __shared__ float red[256];
    float s1 = s_buf[(gat*2+0)*N_NODES + i];
    bool act = (j < N_NODES);
    float e = -INFINITY;
    if (act) {
        float s2 = s_buf[(gat*2+1)*N_NODES + j];
        float z = s1 + s2;
        z = (z > 0.f) ? z : ALPHA * z;
        if (adj[i*N_NODES + j] <= 0) z = -9e15f;
        e = z;
    }
    red[j] = e; __syncthreads();
    for (int s = 128; s > 0; s >>= 1) { if (j < s) red[j] = fmaxf(red[j], red[j+s]); __syncthreads(); }
    float m = red[0]; __syncthreads();
    float val = act ? __expf(e - m) : 0.f;
    red[j] = val; __syncthreads();
    for (int s = 128; s > 0; s >>= 1) { if (j < s) red[j] += red[j+s]; __syncthreads(); }
    float inv = 1.f / red[0];
    if (act) attn[(gat*N_NODES + i)*N_NODES + j] = val * inv;
}

// ---------------- K3: Mbf = bf16(Wih @ attn) zero-padded to K=160,
//                      Whhbf = bf16(Whh), bias = bih + bhh ------------------
__global__ void k_prep(const float* __restrict__ attn,
                       const float* __restrict__ Wih_r, const float* __restrict__ Wih_p,
                       const float* __restrict__ Whh_r, const float* __restrict__ Whh_p,
                       const float* __restrict__ bih_r, const float* __restrict__ bhh_r,
                       const float* __restrict__ bih_p, const float* __restrict__ bhh_p,
                       unsigned short* __restrict__ Mbf /* [2][128][160] */,
                       unsigned short* __restrict__ Whhbf /* [2][128][32] */,
                       float* __restrict__ bias2 /* [2][128] */) {
    int g = blockIdx.x, gat = blockIdx.y;
    const float* Wih = gat ? Wih_p : Wih_r;
    const float* A = attn + gat*N_NODES*N_NODES;
    int j = threadIdx.x;
    if (j < 160) {
        float acc = 0.f;
        if (j < N_NODES)
            for (int n = 0; n < N_NODES; ++n)
                acc = fmaf(Wih[g*N_NODES + n], A[n*N_NODES + j], acc);
        Mbf[(gat*G4 + g)*160 + j] = f2bf(acc);   // j>=156 -> 0
    }
    if (j < HLSTM)
        Whhbf[(gat*G4 + g)*HLSTM + j] = f2bf((gat ? Whh_p : Whh_r)[g*HLSTM + j]);
    if (g == 0 && j < G4)
        bias2[gat*G4 + j] = gat ? (bih_p[j] + bhh_p[j]) : (bih_r[j] + bhh_r[j]);
}

// ---------------- K4: fused gates-MFMA + LSTM + fc --------------------------
// grid 512, block 128 (2 waves). Wave owns 16 batch rows for all 24 steps.
// x staged in LDS (f32) via global_load_lds; ring-4 of 1-step slots; DMAs for
// steps (t, t+1) issued back-to-back INTERLEAVED PER ROW so adjacent 624B
// chunks of each row are in flight together (DRAM page merge -> 1248B runs).
// One counted s_waitcnt vmcnt(20) per even step. Barrier-free (wave-local).
__global__ void __launch_bounds__(NW*64, 1)
k_fused(const float* __restrict__ x,
        const unsigned short* __restrict__ Mbf,    // [2][128][160] bf16, k-padded 0
        const unsigned short* __restrict__ Whhbf,  // [2][128][32] bf16
        const float* __restrict__ bias2,           // [2][128]
        const float* __restrict__ fcW,             // [156][64] f32
        const float* __restrict__ fcb,             // [156]
        float* __restrict__ out) {                 // [16384][156] f32
    __shared__ __align__(16) float xsf[NW][4][SLOTF];        // 78 KB
    __shared__ __align__(16) unsigned short hfrag[NW*512];   // 2 KB  (total 80 KB)

    const int tid = threadIdx.x;
    const int w  = tid >> 6;          // wave
    const int l  = tid & 63;
    const int lm = l & 15;            // MFMA A-row / D-col
    const int lg = l >> 4;            // MFMA k-group / D-row-group
    const int b0 = blockIdx.x * ROWS_B;

    // per-lane DMA source float-offsets: chunk c = l + i*64 over the packed
    // [16 rows][39 chunks of 16B] space; c < 624 always (i==9 masks to l<48)
    unsigned goff[10];
    #pragma unroll
    for (int i = 0; i < 10; ++i) {
        int c = l + i*64;
        if (c > 623) c = 623;                 // masked lanes; keep addr in-bounds
        int r = c / 39;
        int cf = (c - r*39) * 4;
        goff[i] = (unsigned)(r*XSTRIDE + cf);
    }
    const float* xg = x + (size_t)(b0 + 16*w) * XSTRIDE;

    bf16x8 bfr[8][5];     // gates B: [n-tile][k-frag]
    bf16x8 wrec[8];       // rec B
    float  bias_v[8];
    float  cst[8];        // c-state
    unsigned short hrv[8];// h_r kept in regs until epilogue
    const float4 f4z = make_float4(0.f, 0.f, 0.f, 0.f);

#define LOAD_FRAGS(Mb, Wb, bs) do {                                          \
    _Pragma("unroll")                                                        \
    for (int nt = 0; nt < 8; ++nt) {                                         \
        int n_ = nt*16 + lm;                                                 \
        _Pragma("unroll")                                                    \
        for (int kf = 0; kf < 5; ++kf)                                       \
            bfr[nt][kf] = *(const bf16x8*)((Mb) + n_*160 + kf*32 + lg*8);    \
        wrec[nt]   = *(const bf16x8*)((Wb) + n_*HLSTM + lg*8);               \
        bias_v[nt] = (bs)[n_];                                               \
    } } while (0)

    // zero h-state
    #pragma unroll
    for (int ds = 0; ds < 2; ++ds)
        #pragma unroll
        for (int i = 0; i < 4; ++i) {
            hfrag[w*512 + ((lm>>3) + 2*ds)*128 + (lg*4 + i)*8 + (lm&7)] = 0;
            cst[ds*4 + i] = 0.f;
        }
    LOAD_FRAGS(Mbf, Whhbf, bias2);

    // DMA a PAIR of consecutive steps, row-interleaved (page-merge friendly)
#define DMA_PAIR(TA, TB) do {                                                 \
    const float* pa_ = xg + (size_t)(TA)*N_NODES;                             \
    const float* pb_ = xg + (size_t)(TB)*N_NODES;                             \
    float* da_ = &xsf[w][(TA)&3][0];                                          \
    float* db_ = &xsf[w][(TB)&3][0];                                          \
    _Pragma("unroll")                                                         \
    for (int i_ = 0; i_ < 10; ++i_) {                                         \
        if (i_ < 9 || l < 48) {                                               \
            __builtin_amdgcn_global_load_lds(                                 \
                (const __attribute__((address_space(1))) void*)(pa_ + goff[i_]), \
                (__attribute__((address_space(3))) void*)(da_ + i_*256), 16, 0, 0); \
            __builtin_amdgcn_global_load_lds(                                 \
                (const __attribute__((address_space(1))) void*)(pb_ + goff[i_]), \
                (__attribute__((address_space(3))) void*)(db_ + i_*256), 16, 0, 0); \
        }                                                                     \
    } } while (0)

#define WAITVM(N_) asm volatile("s_waitcnt vmcnt(" #N_ ")" ::: "memory")

#define STEP(T_, ISS_) do {                                                   \
    const float* xr_ = &xsf[w][(T_)&3][0] + lm*N_NODES + lg*8;                \
    float4 q0_[5], q1_[5];                                                    \
    _Pragma("unroll")                                                         \
    for (int kf = 0; kf < 5; ++kf) {                                          \
        q0_[kf] = *(const float4*)(xr_ + kf*32);                              \
        q1_[kf] = *(const float4*)(xr_ + kf*32 + 4);                          \
    }                                                                         \
    bf16x8 hf_ = *(const bf16x8*)(hfrag + w*512 + l*8);                       \
    if (lg == 3) q1_[4] = f4z;   /* zero k=156..159 pad */                    \
    bf16x8 af_[5];                                                            \
    _Pragma("unroll")                                                         \
    for (int kf = 0; kf < 5; ++kf) af_[kf] = cv8(q0_[kf], q1_[kf]);           \
    asm volatile("s_waitcnt lgkmcnt(0)" ::: "memory");                        \
    __builtin_amdgcn_sched_barrier(0);                                        \
    if (ISS_) DMA_PAIR((T_)+3, (T_)+4);   /* reuse slots freed at T-1, T */   \
    f32x4 acc[8];                                                             \
    _Pragma("unroll")                                                         \
    for (int nt = 0; nt < 8; ++nt)                                            \
        acc[nt] = (f32x4){bias_v[nt], bias_v[nt], bias_v[nt], bias_v[nt]};    \
    _Pragma("unroll")                                                         \
    for (int kf = 0; kf < 5; ++kf)                                            \
        _Pragma("unroll")                                                     \
        for (int nt = 0; nt < 8; ++nt)                                        \
            acc[nt] = __builtin_amdgcn_mfma_f32_16x16x32_bf16(af_[kf], bfr[nt][kf], acc[nt], 0, 0, 0); \
    _Pragma("unroll")                                                         \
    for (int nt = 0; nt < 8; ++nt)                                            \
        acc[nt] = __builtin_amdgcn_mfma_f32_16x16x32_bf16(hf_, wrec[nt], acc[nt], 0, 0, 0); \
    _Pragma("unroll")                                                         \
    for (int ds = 0; ds < 2; ++ds)                                            \
        _Pragma("unroll")                                                     \
        for (int i = 0; i < 4; ++i) {                                         \
            float si = sigm(acc[0 + ds][i]);                                  \
            float sf = sigm(acc[2 + ds][i]);                                  \
            float tg = tanh_(acc[4 + ds][i]);                                 \
            float so = sigm(acc[6 + ds][i]);                                  \
            float c  = sf * cst[ds*4 + i] + si * tg;                          \
            float h  = so * tanh_(c);                                         \
            int cidx = ((lm>>3) + 2*ds)*128 + (lg*4 + i)*8 + (lm&7);          \
            if ((T_) == 3) {              /* end recent: stash h_r, reset */  \
                hrv[ds*4 + i] = f2bf(h);                                      \
                hfrag[w*512 + cidx]  = 0;                                     \
                cst[ds*4 + i] = 0.f;                                          \
            } else {                                                          \
                cst[ds*4 + i] = c;                                            \
                hfrag[w*512 + cidx] = f2bf(h);                                \
            }                                                                 \
        }                                                                     \
    if ((T_) == 3) LOAD_FRAGS(Mbf + G4*160, Whhbf + G4*HLSTM, bias2 + G4);    \
    } while (0)

    // prologue: fill slots 0..3 as two interleaved pairs (40 DMAs)
    DMA_PAIR(0, 1);
    DMA_PAIR(2, 3);

    for (int p = 0; p < 11; ++p) {          // t = 0..21
        int t0 = 2*p;
        WAITVM(20);                          // pair (t0, t0+1) fully retired
        STEP(t0, 0);
        STEP(t0 + 1, (p < 10));              // issue pair (t0+4, t0+5)
    }
    WAITVM(0);                               // pair (22,23)
    STEP(22, 0);
    STEP(23, 0);

    // ---- fc epilogue: out = [hr|hp] @ fcW^T + fcb (MFMA, K=64) ----
    {
        // redistribute h_r via now-free LDS (slot 0 region)
        unsigned short* hrA = (unsigned short*)&xsf[w][0][0];
        #pragma unroll
        for (int ds = 0; ds < 2; ++ds)
            #pragma unroll
            for (int i = 0; i < 4; ++i) {
                int cidx = ((lm>>3) + 2*ds)*128 + (lg*4 + i)*8 + (lm&7);
                hrA[cidx] = hrv[ds*4 + i];
            }
        asm volatile("s_waitcnt lgkmcnt(0)" ::: "memory");
        __builtin_amdgcn_sched_barrier(0);
        bf16x8 ha0 = *(const bf16x8*)(hrA + l*8);            // h_r frag
        bf16x8 ha1 = *(const bf16x8*)(hfrag + w*512 + l*8);  // h_p frag
        #pragma unroll
        for (int nt = 0; nt < 10; ++nt) {
            int n  = nt*16 + lm;
            int nc = n < 155 ? n : 155;
            const float* wp0 = fcW + nc*64 + lg*8;
            const float* wp1 = fcW + nc*64 + 32 + lg*8;
            bf16x8 wf0 = cv8(*(const float4*)wp0, *(const float4*)(wp0 + 4));
            bf16x8 wf1 = cv8(*(const float4*)wp1, *(const float4*)(wp1 + 4));
            f32x4 fa = (f32x4){0.f, 0.f, 0.f, 0.f};
            fa = __builtin_amdgcn_mfma_f32_16x16x32_bf16(ha0, wf0, fa, 0, 0, 0);
            fa = __builtin_amdgcn_mfma_f32_16x16x32_bf16(ha1, wf1, fa, 0, 0, 0);
            if (n < N_NODES) {
                float bn = fcb[n];
                #pragma unroll
                for (int i = 0; i < 4; ++i)
                    out[(size_t)(b0 + 16*w + lg*4 + i)*N_NODES + n] = fa[i] + bn;
            }
        }
    }
#undef STEP
#undef WAITVM
#undef DMA_PAIR
#undef LOAD_FRAGS
}

extern "C" void kernel_launch(void* const* d_in, const int* in_sizes, int n_in,
                              void* d_out, int out_size, void* d_ws, size_t ws_size,
                              hipStream_t stream) {
    (void)in_sizes; (void)n_in; (void)out_size; (void)ws_size;
    const float* emb   = (const float*)d_in[0];
    const float* x     = (const float*)d_in[1];
    const int*   adj   = (const int*)d_in[2];
    const float* Wr    = (const float*)d_in[3];
    const float* ar    = (const float*)d_in[4];
    const float* Wp    = (const float*)d_in[5];
    const float* ap    = (const float*)d_in[6];
    const float* Wih_r = (const float*)d_in[7];
    const float* Whh_r = (const float*)d_in[8];
    const float* bih_r = (const float*)d_in[9];
    const float* bhh_r = (const float*)d_in[10];
    const float* Wih_p = (const float*)d_in[11];
    const float* Whh_p = (const float*)d_in[12];
    const float* bih_p = (const float*)d_in[13];
    const float* bhh_p = (const float*)d_in[14];
    const float* fcW   = (const float*)d_in[15];
    const float* fcb   = (const float*)d_in[16];
    float* out = (float*)d_out;

    char* ws = (char*)d_ws;
    size_t off = 0;
    auto alloc = [&](size_t bytes) {
        char* p = ws + off;
        off += (bytes + 255) & ~(size_t)255;
        return p;
    };
    float*          attn  = (float*)alloc(2*156*156*sizeof(float));
    float*          sbuf  = (float*)alloc(4*156*sizeof(float));
    unsigned short* Mbf   = (unsigned short*)alloc(2*G4*160*sizeof(unsigned short));
    unsigned short* Whhbf = (unsigned short*)alloc(2*G4*HLSTM*sizeof(unsigned short));
    float*          bias2 = (float*)alloc(2*G4*sizeof(float));

    k_gat_s<<<dim3(156, 2), 128, 0, stream>>>(emb, Wr, ar, Wp, ap, sbuf);
    k_attn<<<dim3(156, 2), 256, 0, stream>>>(sbuf, adj, attn);
    k_prep<<<dim3(128, 2), 192, 0, stream>>>(attn, Wih_r, Wih_p, Whh_r, Whh_p,
                                             bih_r, bhh_r, bih_p, bhh_p,
                                             Mbf, Whhbf, bias2);
    k_fused<<<dim3(BATCH/ROWS_B), NW*64, 0, stream>>>(x, Mbf, Whhbf, bias2, fcW, fcb, out);
}